// Round 9
// baseline (174.532 us; speedup 1.0000x reference)
//
#include <hip/hip_runtime.h>
#include <hip/hip_bf16.h>
#include <math.h>

// Problem dims (fixed)
#define B 4
#define S 1024
#define E 512
#define H 64
#define DK 8
#define FFN 2048
#define BS (B*S)          // 4096 tokens

// kv pre-scale: CSCALE^2 = (1/sqrt(8)) * log2(e) so exp(score/sqrt(8)) = 2^(scaled score)
#define CSCALE 0.7141879f

#if __has_builtin(__builtin_amdgcn_exp2f)
#define EXP2F(x) __builtin_amdgcn_exp2f(x)
#else
#define EXP2F(x) exp2f(x)
#endif

typedef __attribute__((ext_vector_type(8))) short short8;   // 8 bf16 (4 VGPRs)
typedef __attribute__((ext_vector_type(4))) float float4a;  // MFMA C/D frag

union U8 { short8 v; unsigned u[4]; };
union F4 { float4a v; float f[4]; };

__device__ __forceinline__ unsigned short f2bf(float f) {
    unsigned u = __builtin_bit_cast(unsigned, f);
    u = (u + 0x7fffu + ((u >> 16) & 1u)) >> 16;
    return (unsigned short)u;
}
__device__ __forceinline__ float bf2f(unsigned short h) {
    return __builtin_bit_cast(float, (unsigned)h << 16);
}
// one-op pack: (trunc_bf16(a) << 16) | trunc_bf16(b)
__device__ __forceinline__ unsigned packbf(float a, float b) {
    return __builtin_amdgcn_perm(__builtin_bit_cast(unsigned, a),
                                 __builtin_bit_cast(unsigned, b), 0x07060302u);
}
__device__ __forceinline__ unsigned packbf_rn(float a, float b) {
    return ((unsigned)f2bf(a) << 16) | f2bf(b);
}
// key permutation within 32-blocks (attention PV): frag pos g*8+4h+r <-> key 16h+4g+r
__device__ __forceinline__ int pidx(int k) {
    return (k & ~31) | (((k >> 2) & 3) << 3) | (((k >> 4) & 1) << 2) | (k & 3);
}

// async global->LDS, 16B per lane, wave-uniform LDS base (HW adds lane*16)
__device__ __forceinline__ void glds16(const void* g, void* l) {
    __builtin_amdgcn_global_load_lds(
        (const __attribute__((address_space(1))) void*)g,
        (__attribute__((address_space(3))) void*)l, 16, 0, 0);
}

// ---------------------------------------------------------------------------
// K1: [blocks 0..335] weight conversion (runs during ramp-up, not as a tail).
//     [blocks 336..1359] MFMA attention — QUARTER-head blocks (512 thr, 8
//     waves, wave = 2 q-tiles of 16). 1024 attn blocks -> 4 blocks/CU
//     co-resident (LDS 35.3 KB), 32 waves/CU.
//     W1f layout (u16 idx): [0,16384) W1 frag rows f*8; [16384,32768) b1
//     frag rows {b1[f],0..}; [32768,32896) zero pad (g>=2 lanes read here).
// ---------------------------------------------------------------------------
__global__ __launch_bounds__(512) void attn_conv_kernel(const float* __restrict__ x,
                                                        const float* __restrict__ phi,
                                                        const float* __restrict__ Wc,
                                                        const float* __restrict__ W2,
                                                        const float* __restrict__ W1,
                                                        const float* __restrict__ b1,
                                                        unsigned short* __restrict__ Afrag,
                                                        unsigned short* __restrict__ W2f,
                                                        unsigned short* __restrict__ Wcf,
                                                        unsigned short* __restrict__ W1f) {
    __shared__ unsigned short kv[(S + 16) * DK];   // 16.25 KB, rows S..S+15 zero
    __shared__ unsigned short vtp[9][S + 8];       // 18.6 KB [dim0..7 + ones][perm key]
    int bid = blockIdx.x;
    int tid = threadIdx.x;
    const short8 z8 = {0,0,0,0,0,0,0,0};

    if (bid < 336) {                                // ---- convert part (first) ----
        int idx = bid * 512 + tid;
        if (idx < 131072) {                         // W2f (pi-permuted k)
            int lane = idx & 63, c = idx >> 6;
            int ntile = c >> 6, kb32 = c & 63;
            int g = lane >> 4, col = lane & 15;
            int n = ntile * 16 + col, kb = kb32 * 32;
            short8 o;
            #pragma unroll
            for (int j = 0; j < 8; j++) {
                int k = kb + 16 * (j >> 2) + 4 * g + (j & 3);
                o[j] = (short)f2bf(W2[(size_t)k * 512 + n]);
            }
            *(short8*)&W2f[(size_t)idx * 8] = o;
        } else if (idx < 163840) {                  // Wcf (direct frag order)
            int i2 = idx - 131072;
            int lane = i2 & 63, c = i2 >> 6;
            int ntile = c >> 4, kb32 = c & 15;
            int g = lane >> 4, col = lane & 15;
            int n = ntile * 16 + col, kb = kb32 * 32;
            short8 o;
            #pragma unroll
            for (int j = 0; j < 8; j++)
                o[j] = (short)f2bf(Wc[(size_t)(kb + g * 8 + j) * 512 + n]);
            *(short8*)&Wcf[(size_t)i2 * 8] = o;
        } else {                                    // W1f tables
            int i3 = idx - 163840;
            if (i3 < 2048) {                        // W1 frag row f = i3
                short8 o;
                #pragma unroll
                for (int j = 0; j < 8; j++) o[j] = (short)f2bf(W1[j * FFN + i3]);
                *(short8*)&W1f[(size_t)i3 * 8] = o;
            } else if (i3 < 4096) {                 // b1 frag row
                int f = i3 - 2048;
                short8 o = z8;
                o[0] = (short)f2bf(b1[f]);
                *(short8*)&W1f[(size_t)i3 * 8] = o;   // u16 16384 + f*8
            } else if (i3 < 4112) {                 // 256 B zero pad
                *(short8*)&W1f[(size_t)i3 * 8] = z8;  // u16 32768..32896
            }
        }
        return;
    }

    // ---- attention part ----
    int abid = bid - 336;
    int head = abid >> 2, qquad = abid & 3;
    int b = head >> 6, hh = head & 63;

    float ph[DK];
    #pragma unroll
    for (int d = 0; d < DK; d++) ph[d] = phi[d];

    {                                       // 2 consecutive rows per thread
        int r2 = tid * 2;
        unsigned short vb[8][2];
        #pragma unroll
        for (int j = 0; j < 2; j++) {
            const float* xp = x + ((size_t)(b * S + r2 + j)) * E + hh * DK;
            float4 u = *(const float4*)xp;
            float4 v = *(const float4*)(xp + 4);
            float c[8] = {__cosf(u.x+ph[0]), __cosf(u.y+ph[1]), __cosf(u.z+ph[2]), __cosf(u.w+ph[3]),
                          __cosf(v.x+ph[4]), __cosf(v.y+ph[5]), __cosf(v.z+ph[6]), __cosf(v.w+ph[7])};
            U8 kr;
            kr.u[0] = packbf_rn(c[1] * CSCALE, c[0] * CSCALE);
            kr.u[1] = packbf_rn(c[3] * CSCALE, c[2] * CSCALE);
            kr.u[2] = packbf_rn(c[5] * CSCALE, c[4] * CSCALE);
            kr.u[3] = packbf_rn(c[7] * CSCALE, c[6] * CSCALE);
            *(short8*)&kv[(r2 + j) * DK] = kr.v;    // ds_write_b128
            #pragma unroll
            for (int d = 0; d < 8; d++) vb[d][j] = f2bf(c[d]);
        }
        int pr = pidx(r2);                  // even row pair -> adjacent slots
        #pragma unroll
        for (int d = 0; d < 8; d++)
            *(unsigned*)&vtp[d][pr] = (unsigned)vb[d][0] | ((unsigned)vb[d][1] << 16);
        *(unsigned*)&vtp[8][pr] = 0x3F803F80u;      // ones (denominator row)
    }
    if (tid < 16) *(short8*)&kv[(S + tid) * DK] = z8;   // zero rows
    __syncthreads();

    int w = tid >> 6, lane = tid & 63, col = lane & 15, g = lane >> 4;
    bool g0 = (g == 0);
    int q0 = qquad * 256 + w * 32;
    const float4a zc = {0.f,0.f,0.f,0.f};

    short8 aq[2];                            // Q B-frags, 2 q-tiles of 16
    #pragma unroll
    for (int t = 0; t < 2; t++)
        aq[t] = g0 ? *(const short8*)&kv[(q0 + t*16 + col) * DK] : z8;

    float4a acc[2];
    acc[0] = zc; acc[1] = zc;

    int vrow = col < 8 ? col : 8;            // clamp: dims 9..15 get denom dups
    const unsigned short* vbase = &vtp[vrow][0];

    int off0 = g0 ? col * DK : S * DK;       // zero-row pointer trick
    int off1 = g0 ? (16 + col) * DK : S * DK;
    int stepo = g0 ? 32 * DK : 0;

    // prologue: keys for kb=0
    short8 bk0 = *(const short8*)&kv[off0];
    short8 bk1 = *(const short8*)&kv[off1];
    off0 += stepo; off1 += stepo;

    for (int kb = 0; kb < S; kb += 32) {
        // batched QK MFMAs (4 independent)
        __builtin_amdgcn_s_setprio(1);
        float4a s00 = __builtin_amdgcn_mfma_f32_16x16x32_bf16(bk0, aq[0], zc, 0,0,0);
        float4a s01 = __builtin_amdgcn_mfma_f32_16x16x32_bf16(bk1, aq[0], zc, 0,0,0);
        float4a s10 = __builtin_amdgcn_mfma_f32_16x16x32_bf16(bk0, aq[1], zc, 0,0,0);
        float4a s11 = __builtin_amdgcn_mfma_f32_16x16x32_bf16(bk1, aq[1], zc, 0,0,0);
        __builtin_amdgcn_s_setprio(0);
        // current V frag + next-iter keys: ds latency hides under exp phase.
        short8 vf = *(const short8*)(vbase + kb + g * 8);
        short8 nbk0 = *(const short8*)&kv[off0];
        short8 nbk1 = *(const short8*)&kv[off1];
        off0 += stepo; off1 += stepo;
        // exp phase (16 independent trans ops)
        F4 S00, S01, S10, S11;
        S00.v = s00; S01.v = s01; S10.v = s10; S11.v = s11;
        float ea0 = EXP2F(S00.f[0]);
        float ea1 = EXP2F(S00.f[1]);
        float ea2 = EXP2F(S00.f[2]);
        float ea3 = EXP2F(S00.f[3]);
        float eb0 = EXP2F(S01.f[0]);
        float eb1 = EXP2F(S01.f[1]);
        float eb2 = EXP2F(S01.f[2]);
        float eb3 = EXP2F(S01.f[3]);
        float ec0 = EXP2F(S10.f[0]);
        float ec1 = EXP2F(S10.f[1]);
        float ec2 = EXP2F(S10.f[2]);
        float ec3 = EXP2F(S10.f[3]);
        float ed0 = EXP2F(S11.f[0]);
        float ed1 = EXP2F(S11.f[1]);
        float ed2 = EXP2F(S11.f[2]);
        float ed3 = EXP2F(S11.f[3]);
        U8 pf0, pf1;                         // lane-local P^T B-frags
        pf0.u[0] = packbf(ea1, ea0);
        pf0.u[1] = packbf(ea3, ea2);
        pf0.u[2] = packbf(eb1, eb0);
        pf0.u[3] = packbf(eb3, eb2);
        pf1.u[0] = packbf(ec1, ec0);
        pf1.u[1] = packbf(ec3, ec2);
        pf1.u[2] = packbf(ed1, ed0);
        pf1.u[3] = packbf(ed3, ed2);
        __builtin_amdgcn_s_setprio(1);
        acc[0] = __builtin_amdgcn_mfma_f32_16x16x32_bf16(vf, pf0.v, acc[0], 0,0,0);
        acc[1] = __builtin_amdgcn_mfma_f32_16x16x32_bf16(vf, pf1.v, acc[1], 0,0,0);
        __builtin_amdgcn_s_setprio(0);
        bk0 = nbk0; bk1 = nbk1;
    }
    // acc[t]: O'[dim=4g+r][q=col]; denom = dim 8 = lane 32+col, reg 0
    int lp8 = ((hh & 3) * 16 + col) * 8;     // lane' * 8 (u16 units)
    #pragma unroll
    for (int t = 0; t < 2; t++) {
        F4 a; a.v = acc[t];
        float denom = __shfl(a.f[0], 32 + col);
        float inv = __builtin_amdgcn_rcpf(denom);
        if (g < 2) {
            int chunk = (hh >> 2) * 256 + (b * 64 + qquad * 16 + w * 2 + t);
            uint2 o;
            o.x = packbf_rn(a.f[1] * inv, a.f[0] * inv);
            o.y = packbf_rn(a.f[3] * inv, a.f[2] * inv);
            *(uint2*)&Afrag[(size_t)chunk * 512 + lp8 + g * 4] = o;
        }
    }
}

// ---------------------------------------------------------------------------
// K2: combine-heads GEMM + fused LN1 + qout (R8 version, unchanged).
// ---------------------------------------------------------------------------
__global__ __launch_bounds__(512) void combine_ln1(const unsigned short* __restrict__ Afrag,
                                                   const unsigned short* __restrict__ Wcf,
                                                   const float* __restrict__ bc,
                                                   const float* __restrict__ x,
                                                   const float* __restrict__ g1,
                                                   const float* __restrict__ be1,
                                                   float* __restrict__ x1out,
                                                   unsigned short* __restrict__ qoutbf,
                                                   const float* __restrict__ theta) {
    __shared__ unsigned short As[16 * 64 * 8];      // 16 KB
    __shared__ float xout[16][516];                 // 33 KB
    int tt = blockIdx.x;
    int tid = threadIdx.x;
    int w = tid >> 6, lane = tid & 63;
    int wbase = (tid & ~63) * 8;                    // wave chunk base, u16 units

    // async stage As (2 rounds)
    #pragma unroll
    for (int r = 0; r < 2; r++) {
        const unsigned short* gsrc =
            Afrag + ((size_t)((r * 8 + w) * 256 + tt) * 64 + lane) * 8;
        glds16(gsrc, &As[r * 4096 + wbase]);
    }
    asm volatile("s_waitcnt vmcnt(0)" ::: "memory");
    __syncthreads();

    int col = lane & 15, g = lane >> 4;
    const float4a zc = {0.f,0.f,0.f,0.f};
    float4a acc[4];
    #pragma unroll
    for (int nt = 0; nt < 4; nt++) acc[nt] = zc;

    // wave w owns ntiles w*4 .. w*4+3; frag (nt,kb32) at wp + nt*8192 + kb32*512
    const unsigned short* wp = Wcf + ((size_t)(w * 4096) + lane) * 8;

    short8 bfA[4], bfB[4];
    #pragma unroll
    for (int nt = 0; nt < 4; nt++)
        bfA[nt] = *(const short8*)(wp + nt * 8192);

    for (int kb32 = 0; kb32 < 16; kb32 += 2) {
        #pragma unroll
        for (int nt = 0; nt < 4; nt++)
            bfB[nt] = *(const short8*)(wp + nt * 8192 + (kb32 + 1) * 512);
        short8 af = *(const short8*)&As[(kb32 * 64 + lane) * 8];
        #pragma unroll
        for (int nt = 0; nt < 4; nt++)
            acc[nt] = __builtin_amdgcn_mfma_f32_16x16x32_bf16(af, bfA[nt], acc[nt], 0, 0, 0);
        if (kb32 + 2 < 16) {
            #pragma unroll
            for (int nt = 0; nt < 4; nt++)
                bfA[nt] = *(const short8*)(wp + nt * 8192 + (kb32 + 2) * 512);
        }
        af = *(const short8*)&As[((kb32 + 1) * 64 + lane) * 8];
        #pragma unroll
        for (int nt = 0; nt < 4; nt++)
            acc[nt] = __builtin_amdgcn_mfma_f32_16x16x32_bf16(af, bfB[nt], acc[nt], 0, 0, 0);
    }
    #pragma unroll
    for (int nt = 0; nt < 4; nt++) {
        int n = w * 64 + nt * 16 + col;
        float bb = bc[n];
        #pragma unroll
        for (int r = 0; r < 4; r++)
            xout[g * 4 + r][n] = acc[nt][r] + bb;
    }
    __syncthreads();

    int hl = lane >> 5, l = lane & 31;
    int token = w * 2 + hl;
    int e0 = l * 16;
    size_t grow = ((size_t)tt * 16 + token) * 512;
    float v[16];
    float s = 0.f, sq = 0.f;
    #pragma unroll
    for (int u = 0; u < 4; u++) {
        float4 xv = *(const float4*)&x[grow + e0 + u * 4];
        float4 pv = *(const float4*)&xout[token][e0 + u * 4];
        float a0 = xv.x + pv.x, a1 = xv.y + pv.y, a2 = xv.z + pv.z, a3 = xv.w + pv.w;
        v[u*4] = a0; v[u*4+1] = a1; v[u*4+2] = a2; v[u*4+3] = a3;
        s += a0 + a1 + a2 + a3;
        sq += a0*a0 + a1*a1 + a2*a2 + a3*a3;
    }
    #pragma unroll
    for (int off = 1; off <= 16; off <<= 1) {
        s  += __shfl_xor(s, off);
        sq += __shfl_xor(sq, off);
    }
    float mu = s * (1.f / 512.f);
    float var = sq * (1.f / 512.f) - mu * mu;
    float rstd = rsqrtf(var + 1e-5f);
    float y[16];
    #pragma unroll
    for (int u = 0; u < 4; u++) {
        float4 gv = *(const float4*)&g1[e0 + u * 4];
        float4 bv = *(const float4*)&be1[e0 + u * 4];
        y[u*4]   = (v[u*4]   - mu) * rstd * gv.x + bv.x;
        y[u*4+1] = (v[u*4+1] - mu) * rstd * gv.y + bv.y;
        y[u*4+2] = (v[u*4+2] - mu) * rstd * gv.z + bv.z;
        y[u*4+3] = (v[u*4+3] - mu) * rstd * gv.w + bv.w;
        float4 o = make_float4(y[u*4], y[u*4+1], y[u*4+2], y[u*4+3]);
        *(float4*)&x1out[grow + e0 + u * 4] = o;
    }
    if (l == 0) {
        U8 q;
        q.u[0] = packbf_rn(__cosf(y[1]) * __cosf(theta[1]), __cosf(y[0]) * __cosf(theta[0]));
        q.u[1] = packbf_rn(__cosf(y[3]) * __cosf(theta[3]), __cosf(y[2]) * __cosf(theta[2]));
        q.u[2] = packbf_rn(__cosf(y[5]) * __cosf(theta[5]), __cosf(y[4]) * __cosf(theta[4]));
        q.u[3] = packbf_rn(__cosf(y[7]) * __cosf(theta[7]), __cosf(y[6]) * __cosf(theta[6]));
        *(short8*)&qoutbf[((size_t)tt * 16 + token) * 8] = q.v;
    }
}

// ---------------------------------------------------------------------------
// K3': FFN + fused LN2. 256 blocks x 512 thr (8 waves), 1 blk/CU, 8 waves/CU
// (same TLP as R8's K3: 2 waves/SIMD). Wave = 16 tok x 64 n over FULL k
// (64 kb32 iters) — per-wave totals identical to R8 (128 h-MFMA + 256
// acc-MFMA, same VALU:MFMA ratio, same W2f load count). Block owns complete
// 512-n rows for its 16 tokens -> LN2 fuses as epilogue: K4 and one kernel
// boundary deleted; ffn_out stays fp32 (no bf16 round-trip through HBM).
// W1/W2 frags register-prefetched one k-iter ahead (per-lane base pointers:
// g=0 W1 frags, g=1 b1 frags, g>=2 zero pad).
// ---------------------------------------------------------------------------
__global__ __launch_bounds__(512) void ffn_ln2(const unsigned short* __restrict__ qbf,
                                               const unsigned short* __restrict__ W1fg,
                                               const unsigned short* __restrict__ W2f,
                                               const float* __restrict__ b2,
                                               const float* __restrict__ g2,
                                               const float* __restrict__ be2,
                                               float* __restrict__ out) {
    __shared__ float sums[8][16], sqs[8][16];  // 1 KB cross-wave LN reduce
    int tid = threadIdx.x;
    int w = tid >> 6, lane = tid & 63, col = lane & 15, g = lane >> 4;
    int mw = blockIdx.x * 16;                  // 16 tokens per block
    int ntile0 = w * 4;                        // wave covers n [w*64, w*64+64)
    const short8 z8 = {0,0,0,0,0,0,0,0};
    const short8 one8 = {(short)0x3F80,0,0,0,0,0,0,0};
    const float4a zc = {0.f,0.f,0.f,0.f};

    short8 qf = (g == 0) ? *(const short8*)&qbf[(size_t)(mw + col) * 8]
                         : (g == 1 ? one8 : z8);

    float4a acc[4];
    #pragma unroll
    for (int nt = 0; nt < 4; nt++) acc[nt] = zc;

    const unsigned short* w2p = W2f + (size_t)ntile0 * 64 * 512 + lane * 8;
    // per-lane W1 base: g=0 -> W1 frag rows, g=1 -> b1 frag rows, g>=2 -> zeros
    const unsigned short* w1p =
        (g == 0) ? W1fg + (size_t)col * 8 :
        (g == 1) ? W1fg + 16384 + (size_t)col * 8 :
                   W1fg + 32768;
    int w1step = (g < 2) ? 256 : 0;            // u16 per kb32 iter

    short8 afA[4], afB[4], w1A0, w1A1, w1B0, w1B1;
    #pragma unroll
    for (int nt = 0; nt < 4; nt++)
        afA[nt] = *(const short8*)(w2p + nt * 32768);
    w1A0 = *(const short8*)w1p;
    w1A1 = *(const short8*)(w1p + 128);
    w1p += w1step;

#define FFN_BODY(AF, W10, W11)                                                    \
    {                                                                             \
        float4a h0 = __builtin_amdgcn_mfma_f32_16x16x32_bf16(W10, qf, zc, 0,0,0); \
        float4a h1 = __builtin_amdgcn_mfma_f32_16x16x32_bf16(W11, qf, zc, 0,0,0); \
        F4 H0, H1; H0.v = h0; H1.v = h1;                                          \
        float e00 = fmaxf(H0.f[0], 0.f);                                          \
        float e01 = fmaxf(H0.f[1], 0.f);                                          \
        float e02 = fmaxf(H0.f[2], 0.f);                                          \
        float e03 = fmaxf(H0.f[3], 0.f);                                          \
        float e10 = fmaxf(H1.f[0], 0.f);                                          \
        float e11 = fmaxf(H1.f[1], 0.f);                                          \
        float e12 = fmaxf(H1.f[2], 0.f);                                          \
        float e13 = fmaxf(H1.f[3], 0.f);                                          \
        U8 pf;                                                                    \
        pf.u[0] = packbf(e01, e00);                                               \
        pf.u[1] = packbf(e03, e02);                                               \
        pf.u[2] = packbf(e11, e10);                                               \
        pf.u[3] = packbf(e13, e12);                                               \
        _Pragma("unroll")                                                         \
        for (int nt = 0; nt < 4; nt++)                                            \
            acc[nt] = __builtin_amdgcn_mfma_f32_16x16x32_bf16(AF[nt], pf.v,       \
                                                              acc[nt], 0,0,0);    \
    }

    for (int kb32 = 0; kb32 < 64; kb32 += 2) {
        // prefetch odd iter
        #pragma unroll
        for (int nt = 0; nt < 4; nt++)
            afB[nt] = *(const short8*)(w2p + nt * 32768 + (size_t)(kb32 + 1) * 512);
        w1B0 = *(const short8*)w1p;
        w1B1 = *(const short8*)(w1p + 128);
        w1p += w1step;
        FFN_BODY(afA, w1A0, w1A1)
        // prefetch next even iter (final round reads spill into adjacent
        // mapped workspace regions; values discarded)
        #pragma unroll
        for (int nt = 0; nt < 4; nt++)
            afA[nt] = *(const short8*)(w2p + nt * 32768 + (size_t)(kb32 + 2) * 512);
        w1A0 = *(const short8*)w1p;
        w1A1 = *(const short8*)(w1p + 128);
        w1p += w1step;
        FFN_BODY(afB, w1B0, w1B1)
    }
#undef FFN_BODY

    // ---- fused LN2 epilogue ----
    // thread holds ffn acc for token t = mw+col at n = w*64 + nt*16 + 4g + r
    int t = mw + col;
    size_t base = (size_t)t * E;
    int nb = w * 64 + 4 * g;
    float v[16];
    float s = 0.f, sq = 0.f;
    #pragma unroll
    for (int nt = 0; nt < 4; nt++) {
        float4 bb = *(const float4*)&b2[nb + nt * 16];
        float4 xv = *(const float4*)&out[base + nb + nt * 16];   // x1 (fp32)
        F4 a; a.v = acc[nt];
        float v0 = xv.x + a.f[0] + bb.x;
        float v1 = xv.y + a.f[1] + bb.y;
        float v2 = xv.z + a.f[2] + bb.z;
        float v3 = xv.w + a.f[3] + bb.w;
        v[nt*4] = v0; v[nt*4+1] = v1; v[nt*4+2] = v2; v[nt*4+3] = v3;
        s += v0 + v1 + v2 + v3;
        sq += v0*v0 + v1*v1 + v2*v2 + v3*v3;
    }
    // reduce over g (token t lives in lanes col, col+16, col+32, col+48)
    s  += __shfl_xor(s, 16);  sq += __shfl_xor(sq, 16);
    s  += __shfl_xor(s, 32);  sq += __shfl_xor(sq, 32);
    if (lane < 16) { sums[w][col] = s; sqs[w][col] = sq; }
    __syncthreads();
    float SS = 0.f, QQ = 0.f;
    #pragma unroll
    for (int ww = 0; ww < 8; ww++) { SS += sums[ww][col]; QQ += sqs[ww][col]; }
    float mu = SS * (1.f / E);
    float var = QQ * (1.f / E) - mu * mu;
    float rstd = rsqrtf(var + 1e-5f);
    #pragma unroll
    for (int nt = 0; nt < 4; nt++) {
        float4 gv = *(const float4*)&g2[nb + nt * 16];
        float4 bv = *(const float4*)&be2[nb + nt * 16];
        float4 o;
        o.x = (v[nt*4]   - mu) * rstd * gv.x + bv.x;
        o.y = (v[nt*4+1] - mu) * rstd * gv.y + bv.y;
        o.z = (v[nt*4+2] - mu) * rstd * gv.z + bv.z;
        o.w = (v[nt*4+3] - mu) * rstd * gv.w + bv.w;
        *(float4*)&out[base + nb + nt * 16] = o;
    }
}

// ---------------------------------------------------------------------------
// launch — 3 kernels. ws: Afrag 4MB | W2f 2MB | Wcf 0.5MB | W1f 128KB
// | qoutbf 64KB = 6.7 MB. d_out: x1 fp32, FFN+LN2 in-place.
// ---------------------------------------------------------------------------
extern "C" void kernel_launch(void* const* d_in, const int* in_sizes, int n_in,
                              void* d_out, int out_size, void* d_ws, size_t ws_size,
                              hipStream_t stream) {
    const float* x     = (const float*)d_in[0];
    const float* phi   = (const float*)d_in[1];
    const float* Wc    = (const float*)d_in[2];
    const float* bc    = (const float*)d_in[3];
    const float* theta = (const float*)d_in[4];
    const float* W1    = (const float*)d_in[5];
    const float* b1    = (const float*)d_in[6];
    const float* W2    = (const float*)d_in[7];
    const float* b2    = (const float*)d_in[8];
    const float* g1    = (const float*)d_in[9];
    const float* be1   = (const float*)d_in[10];
    const float* g2    = (const float*)d_in[11];
    const float* be2   = (const float*)d_in[12];
    float* out = (float*)d_out;

    float* ws = (float*)d_ws;
    unsigned short* Afrag  = (unsigned short*)ws;                       // 4 MB
    unsigned short* W2f    = (unsigned short*)(ws + 1048576);           // 2 MB
    unsigned short* Wcf    = (unsigned short*)(ws + 1572864);           // 512 KB
    unsigned short* W1f    = (unsigned short*)(ws + 1703936);           // 128 KB
    unsigned short* qoutbf = (unsigned short*)(ws + 1736704);           // 64 KB

    attn_conv_kernel<<<1360, 512, 0, stream>>>(x, phi, Wc, W2, W1, b1,
                                               Afrag, W2f, Wcf, W1f);
    combine_ln1<<<256, 512, 0, stream>>>(Afrag, Wcf, bc, x, g1, be1,
                                         out, qoutbf, theta);
    ffn_ln2<<<256, 512, 0, stream>>>(qoutbf, W1f, W2f, b2, g2, be2, out);
}

// Round 10
// 154.734 us; speedup vs baseline: 1.1279x; 1.1279x over previous
//
#include <hip/hip_runtime.h>
#include <hip/hip_bf16.h>
#include <math.h>

// Problem dims (fixed)
#define B 4
#define S 1024
#define E 512
#define H 64
#define DK 8
#define FFN 2048
#define BS (B*S)          // 4096 tokens

// kv pre-scale: CSCALE^2 = (1/sqrt(8)) * log2(e) so exp(score/sqrt(8)) = 2^(scaled score)
#define CSCALE 0.7141879f

#if __has_builtin(__builtin_amdgcn_exp2f)
#define EXP2F(x) __builtin_amdgcn_exp2f(x)
#else
#define EXP2F(x) exp2f(x)
#endif

typedef __attribute__((ext_vector_type(8))) short short8;   // 8 bf16 (4 VGPRs)
typedef __attribute__((ext_vector_type(4))) float float4a;  // MFMA C/D frag

union U8 { short8 v; unsigned u[4]; };
union F4 { float4a v; float f[4]; };

__device__ __forceinline__ unsigned short f2bf(float f) {
    unsigned u = __builtin_bit_cast(unsigned, f);
    u = (u + 0x7fffu + ((u >> 16) & 1u)) >> 16;
    return (unsigned short)u;
}
__device__ __forceinline__ float bf2f(unsigned short h) {
    return __builtin_bit_cast(float, (unsigned)h << 16);
}
// one-op pack: (trunc_bf16(a) << 16) | trunc_bf16(b)
__device__ __forceinline__ unsigned packbf(float a, float b) {
    return __builtin_amdgcn_perm(__builtin_bit_cast(unsigned, a),
                                 __builtin_bit_cast(unsigned, b), 0x07060302u);
}
__device__ __forceinline__ unsigned packbf_rn(float a, float b) {
    return ((unsigned)f2bf(a) << 16) | f2bf(b);
}
// key permutation within 32-blocks (attention PV): frag pos g*8+4h+r <-> key 16h+4g+r
__device__ __forceinline__ int pidx(int k) {
    return (k & ~31) | (((k >> 2) & 3) << 3) | (((k >> 4) & 1) << 2) | (k & 3);
}

// async global->LDS, 16B per lane, wave-uniform LDS base (HW adds lane*16)
__device__ __forceinline__ void glds16(const void* g, void* l) {
    __builtin_amdgcn_global_load_lds(
        (const __attribute__((address_space(1))) void*)g,
        (__attribute__((address_space(3))) void*)l, 16, 0, 0);
}

// ---------------------------------------------------------------------------
// K1: [blocks 0..335] weight conversion (runs during ramp-up, not as a tail).
//     [blocks 336..1359] MFMA attention — QUARTER-head blocks (512 thr, 8
//     waves, wave = 2 q-tiles of 16). 1024 attn blocks -> 4 blocks/CU
//     co-resident (LDS 35.3 KB), 32 waves/CU.
//     W1f layout (u16 idx): [0,16384) W1 frag rows f*8; [16384,32768) b1
//     frag rows {b1[f],0..}; [32768,32896) zero pad (g>=2 lanes read here).
// ---------------------------------------------------------------------------
__global__ __launch_bounds__(512) void attn_conv_kernel(const float* __restrict__ x,
                                                        const float* __restrict__ phi,
                                                        const float* __restrict__ Wc,
                                                        const float* __restrict__ W2,
                                                        const float* __restrict__ W1,
                                                        const float* __restrict__ b1,
                                                        unsigned short* __restrict__ Afrag,
                                                        unsigned short* __restrict__ W2f,
                                                        unsigned short* __restrict__ Wcf,
                                                        unsigned short* __restrict__ W1f) {
    __shared__ unsigned short kv[(S + 16) * DK];   // 16.25 KB, rows S..S+15 zero
    __shared__ unsigned short vtp[9][S + 8];       // 18.6 KB [dim0..7 + ones][perm key]
    int bid = blockIdx.x;
    int tid = threadIdx.x;
    const short8 z8 = {0,0,0,0,0,0,0,0};

    if (bid < 336) {                                // ---- convert part (first) ----
        int idx = bid * 512 + tid;
        if (idx < 131072) {                         // W2f (pi-permuted k)
            int lane = idx & 63, c = idx >> 6;
            int ntile = c >> 6, kb32 = c & 63;
            int g = lane >> 4, col = lane & 15;
            int n = ntile * 16 + col, kb = kb32 * 32;
            short8 o;
            #pragma unroll
            for (int j = 0; j < 8; j++) {
                int k = kb + 16 * (j >> 2) + 4 * g + (j & 3);
                o[j] = (short)f2bf(W2[(size_t)k * 512 + n]);
            }
            *(short8*)&W2f[(size_t)idx * 8] = o;
        } else if (idx < 163840) {                  // Wcf (direct frag order)
            int i2 = idx - 131072;
            int lane = i2 & 63, c = i2 >> 6;
            int ntile = c >> 4, kb32 = c & 15;
            int g = lane >> 4, col = lane & 15;
            int n = ntile * 16 + col, kb = kb32 * 32;
            short8 o;
            #pragma unroll
            for (int j = 0; j < 8; j++)
                o[j] = (short)f2bf(Wc[(size_t)(kb + g * 8 + j) * 512 + n]);
            *(short8*)&Wcf[(size_t)i2 * 8] = o;
        } else {                                    // W1f tables
            int i3 = idx - 163840;
            if (i3 < 2048) {                        // W1 frag row f = i3
                short8 o;
                #pragma unroll
                for (int j = 0; j < 8; j++) o[j] = (short)f2bf(W1[j * FFN + i3]);
                *(short8*)&W1f[(size_t)i3 * 8] = o;
            } else if (i3 < 4096) {                 // b1 frag row
                int f = i3 - 2048;
                short8 o = z8;
                o[0] = (short)f2bf(b1[f]);
                *(short8*)&W1f[(size_t)i3 * 8] = o;   // u16 16384 + f*8
            } else if (i3 < 4112) {                 // 256 B zero pad
                *(short8*)&W1f[(size_t)i3 * 8] = z8;  // u16 32768..32896
            }
        }
        return;
    }

    // ---- attention part ----
    int abid = bid - 336;
    int head = abid >> 2, qquad = abid & 3;
    int b = head >> 6, hh = head & 63;

    float ph[DK];
    #pragma unroll
    for (int d = 0; d < DK; d++) ph[d] = phi[d];

    {                                       // 2 consecutive rows per thread
        int r2 = tid * 2;
        unsigned short vb[8][2];
        #pragma unroll
        for (int j = 0; j < 2; j++) {
            const float* xp = x + ((size_t)(b * S + r2 + j)) * E + hh * DK;
            float4 u = *(const float4*)xp;
            float4 v = *(const float4*)(xp + 4);
            float c[8] = {__cosf(u.x+ph[0]), __cosf(u.y+ph[1]), __cosf(u.z+ph[2]), __cosf(u.w+ph[3]),
                          __cosf(v.x+ph[4]), __cosf(v.y+ph[5]), __cosf(v.z+ph[6]), __cosf(v.w+ph[7])};
            U8 kr;
            kr.u[0] = packbf_rn(c[1] * CSCALE, c[0] * CSCALE);
            kr.u[1] = packbf_rn(c[3] * CSCALE, c[2] * CSCALE);
            kr.u[2] = packbf_rn(c[5] * CSCALE, c[4] * CSCALE);
            kr.u[3] = packbf_rn(c[7] * CSCALE, c[6] * CSCALE);
            *(short8*)&kv[(r2 + j) * DK] = kr.v;    // ds_write_b128
            #pragma unroll
            for (int d = 0; d < 8; d++) vb[d][j] = f2bf(c[d]);
        }
        int pr = pidx(r2);                  // even row pair -> adjacent slots
        #pragma unroll
        for (int d = 0; d < 8; d++)
            *(unsigned*)&vtp[d][pr] = (unsigned)vb[d][0] | ((unsigned)vb[d][1] << 16);
        *(unsigned*)&vtp[8][pr] = 0x3F803F80u;      // ones (denominator row)
    }
    if (tid < 16) *(short8*)&kv[(S + tid) * DK] = z8;   // zero rows
    __syncthreads();

    int w = tid >> 6, lane = tid & 63, col = lane & 15, g = lane >> 4;
    bool g0 = (g == 0);
    int q0 = qquad * 256 + w * 32;
    const float4a zc = {0.f,0.f,0.f,0.f};

    short8 aq[2];                            // Q B-frags, 2 q-tiles of 16
    #pragma unroll
    for (int t = 0; t < 2; t++)
        aq[t] = g0 ? *(const short8*)&kv[(q0 + t*16 + col) * DK] : z8;

    float4a acc[2];
    acc[0] = zc; acc[1] = zc;

    int vrow = col < 8 ? col : 8;            // clamp: dims 9..15 get denom dups
    const unsigned short* vbase = &vtp[vrow][0];

    int off0 = g0 ? col * DK : S * DK;       // zero-row pointer trick
    int off1 = g0 ? (16 + col) * DK : S * DK;
    int stepo = g0 ? 32 * DK : 0;

    // prologue: keys for kb=0
    short8 bk0 = *(const short8*)&kv[off0];
    short8 bk1 = *(const short8*)&kv[off1];
    off0 += stepo; off1 += stepo;

    for (int kb = 0; kb < S; kb += 32) {
        // batched QK MFMAs (4 independent)
        __builtin_amdgcn_s_setprio(1);
        float4a s00 = __builtin_amdgcn_mfma_f32_16x16x32_bf16(bk0, aq[0], zc, 0,0,0);
        float4a s01 = __builtin_amdgcn_mfma_f32_16x16x32_bf16(bk1, aq[0], zc, 0,0,0);
        float4a s10 = __builtin_amdgcn_mfma_f32_16x16x32_bf16(bk0, aq[1], zc, 0,0,0);
        float4a s11 = __builtin_amdgcn_mfma_f32_16x16x32_bf16(bk1, aq[1], zc, 0,0,0);
        __builtin_amdgcn_s_setprio(0);
        // current V frag + next-iter keys: ds latency hides under exp phase.
        short8 vf = *(const short8*)(vbase + kb + g * 8);
        short8 nbk0 = *(const short8*)&kv[off0];
        short8 nbk1 = *(const short8*)&kv[off1];
        off0 += stepo; off1 += stepo;
        // exp phase (16 independent trans ops)
        F4 S00, S01, S10, S11;
        S00.v = s00; S01.v = s01; S10.v = s10; S11.v = s11;
        float ea0 = EXP2F(S00.f[0]);
        float ea1 = EXP2F(S00.f[1]);
        float ea2 = EXP2F(S00.f[2]);
        float ea3 = EXP2F(S00.f[3]);
        float eb0 = EXP2F(S01.f[0]);
        float eb1 = EXP2F(S01.f[1]);
        float eb2 = EXP2F(S01.f[2]);
        float eb3 = EXP2F(S01.f[3]);
        float ec0 = EXP2F(S10.f[0]);
        float ec1 = EXP2F(S10.f[1]);
        float ec2 = EXP2F(S10.f[2]);
        float ec3 = EXP2F(S10.f[3]);
        float ed0 = EXP2F(S11.f[0]);
        float ed1 = EXP2F(S11.f[1]);
        float ed2 = EXP2F(S11.f[2]);
        float ed3 = EXP2F(S11.f[3]);
        U8 pf0, pf1;                         // lane-local P^T B-frags
        pf0.u[0] = packbf(ea1, ea0);
        pf0.u[1] = packbf(ea3, ea2);
        pf0.u[2] = packbf(eb1, eb0);
        pf0.u[3] = packbf(eb3, eb2);
        pf1.u[0] = packbf(ec1, ec0);
        pf1.u[1] = packbf(ec3, ec2);
        pf1.u[2] = packbf(ed1, ed0);
        pf1.u[3] = packbf(ed3, ed2);
        __builtin_amdgcn_s_setprio(1);
        acc[0] = __builtin_amdgcn_mfma_f32_16x16x32_bf16(vf, pf0.v, acc[0], 0,0,0);
        acc[1] = __builtin_amdgcn_mfma_f32_16x16x32_bf16(vf, pf1.v, acc[1], 0,0,0);
        __builtin_amdgcn_s_setprio(0);
        bk0 = nbk0; bk1 = nbk1;
    }
    // acc[t]: O'[dim=4g+r][q=col]; denom = dim 8 = lane 32+col, reg 0
    int lp8 = ((hh & 3) * 16 + col) * 8;     // lane' * 8 (u16 units)
    #pragma unroll
    for (int t = 0; t < 2; t++) {
        F4 a; a.v = acc[t];
        float denom = __shfl(a.f[0], 32 + col);
        float inv = __builtin_amdgcn_rcpf(denom);
        if (g < 2) {
            int chunk = (hh >> 2) * 256 + (b * 64 + qquad * 16 + w * 2 + t);
            uint2 o;
            o.x = packbf_rn(a.f[1] * inv, a.f[0] * inv);
            o.y = packbf_rn(a.f[3] * inv, a.f[2] * inv);
            *(uint2*)&Afrag[(size_t)chunk * 512 + lp8 + g * 4] = o;
        }
    }
}

// ---------------------------------------------------------------------------
// K2: combine-heads GEMM + fused LN1 + qout.
// Wcf LDS staging deleted (zero inter-wave reuse). Each wave reads its Wcf
// slice directly from L2 with a 1-iter register double-buffer; ZERO barriers
// in the k-loop. As staged in LDS (true 8-wave reuse).
// ---------------------------------------------------------------------------
__global__ __launch_bounds__(512) void combine_ln1(const unsigned short* __restrict__ Afrag,
                                                   const unsigned short* __restrict__ Wcf,
                                                   const float* __restrict__ bc,
                                                   const float* __restrict__ x,
                                                   const float* __restrict__ g1,
                                                   const float* __restrict__ be1,
                                                   float* __restrict__ x1out,
                                                   unsigned short* __restrict__ qoutbf,
                                                   const float* __restrict__ theta) {
    __shared__ unsigned short As[16 * 64 * 8];      // 16 KB
    __shared__ float xout[16][516];                 // 33 KB
    int tt = blockIdx.x;
    int tid = threadIdx.x;
    int w = tid >> 6, lane = tid & 63;
    int wbase = (tid & ~63) * 8;                    // wave chunk base, u16 units

    // async stage As (2 rounds)
    #pragma unroll
    for (int r = 0; r < 2; r++) {
        const unsigned short* gsrc =
            Afrag + ((size_t)((r * 8 + w) * 256 + tt) * 64 + lane) * 8;
        glds16(gsrc, &As[r * 4096 + wbase]);
    }
    asm volatile("s_waitcnt vmcnt(0)" ::: "memory");
    __syncthreads();

    int col = lane & 15, g = lane >> 4;
    const float4a zc = {0.f,0.f,0.f,0.f};
    float4a acc[4];
    #pragma unroll
    for (int nt = 0; nt < 4; nt++) acc[nt] = zc;

    // wave w owns ntiles w*4 .. w*4+3; frag (nt,kb32) at wp + nt*8192 + kb32*512
    const unsigned short* wp = Wcf + ((size_t)(w * 4096) + lane) * 8;

    short8 bfA[4], bfB[4];
    #pragma unroll
    for (int nt = 0; nt < 4; nt++)
        bfA[nt] = *(const short8*)(wp + nt * 8192);

    for (int kb32 = 0; kb32 < 16; kb32 += 2) {
        #pragma unroll
        for (int nt = 0; nt < 4; nt++)
            bfB[nt] = *(const short8*)(wp + nt * 8192 + (kb32 + 1) * 512);
        short8 af = *(const short8*)&As[(kb32 * 64 + lane) * 8];
        #pragma unroll
        for (int nt = 0; nt < 4; nt++)
            acc[nt] = __builtin_amdgcn_mfma_f32_16x16x32_bf16(af, bfA[nt], acc[nt], 0, 0, 0);
        if (kb32 + 2 < 16) {
            #pragma unroll
            for (int nt = 0; nt < 4; nt++)
                bfA[nt] = *(const short8*)(wp + nt * 8192 + (kb32 + 2) * 512);
        }
        af = *(const short8*)&As[((kb32 + 1) * 64 + lane) * 8];
        #pragma unroll
        for (int nt = 0; nt < 4; nt++)
            acc[nt] = __builtin_amdgcn_mfma_f32_16x16x32_bf16(af, bfB[nt], acc[nt], 0, 0, 0);
    }
    #pragma unroll
    for (int nt = 0; nt < 4; nt++) {
        int n = w * 64 + nt * 16 + col;
        float bb = bc[n];
        #pragma unroll
        for (int r = 0; r < 4; r++)
            xout[g * 4 + r][n] = acc[nt][r] + bb;
    }
    __syncthreads();

    int hl = lane >> 5, l = lane & 31;
    int token = w * 2 + hl;
    int e0 = l * 16;
    size_t grow = ((size_t)tt * 16 + token) * 512;
    float v[16];
    float s = 0.f, sq = 0.f;
    #pragma unroll
    for (int u = 0; u < 4; u++) {
        float4 xv = *(const float4*)&x[grow + e0 + u * 4];
        float4 pv = *(const float4*)&xout[token][e0 + u * 4];
        float a0 = xv.x + pv.x, a1 = xv.y + pv.y, a2 = xv.z + pv.z, a3 = xv.w + pv.w;
        v[u*4] = a0; v[u*4+1] = a1; v[u*4+2] = a2; v[u*4+3] = a3;
        s += a0 + a1 + a2 + a3;
        sq += a0*a0 + a1*a1 + a2*a2 + a3*a3;
    }
    #pragma unroll
    for (int off = 1; off <= 16; off <<= 1) {
        s  += __shfl_xor(s, off);
        sq += __shfl_xor(sq, off);
    }
    float mu = s * (1.f / 512.f);
    float var = sq * (1.f / 512.f) - mu * mu;
    float rstd = rsqrtf(var + 1e-5f);
    float y[16];
    #pragma unroll
    for (int u = 0; u < 4; u++) {
        float4 gv = *(const float4*)&g1[e0 + u * 4];
        float4 bv = *(const float4*)&be1[e0 + u * 4];
        y[u*4]   = (v[u*4]   - mu) * rstd * gv.x + bv.x;
        y[u*4+1] = (v[u*4+1] - mu) * rstd * gv.y + bv.y;
        y[u*4+2] = (v[u*4+2] - mu) * rstd * gv.z + bv.z;
        y[u*4+3] = (v[u*4+3] - mu) * rstd * gv.w + bv.w;
        float4 o = make_float4(y[u*4], y[u*4+1], y[u*4+2], y[u*4+3]);
        *(float4*)&x1out[grow + e0 + u * 4] = o;
    }
    if (l == 0) {
        U8 q;
        q.u[0] = packbf_rn(__cosf(y[1]) * __cosf(theta[1]), __cosf(y[0]) * __cosf(theta[0]));
        q.u[1] = packbf_rn(__cosf(y[3]) * __cosf(theta[3]), __cosf(y[2]) * __cosf(theta[2]));
        q.u[2] = packbf_rn(__cosf(y[5]) * __cosf(theta[5]), __cosf(y[4]) * __cosf(theta[4]));
        q.u[3] = packbf_rn(__cosf(y[7]) * __cosf(theta[7]), __cosf(y[6]) * __cosf(theta[6]));
        *(short8*)&qoutbf[((size_t)tt * 16 + token) * 8] = q.v;
    }
}

// ---------------------------------------------------------------------------
// K3: FFN — k-split x2, NO LDS staging. W1 operand via per-lane base pointer
// (g=0: W1 frags, g=1: b1 frags, g>=2: zero pad). W1 + W2 frags register-
// prefetched one k-iter ahead. 512 blk x 256 thr, 2 waves/SIMD.
// ---------------------------------------------------------------------------
__global__ __launch_bounds__(256) void ffn_mfma(const unsigned short* __restrict__ qbf,
                                                const unsigned short* __restrict__ W1fg,
                                                const unsigned short* __restrict__ W2f,
                                                const float* __restrict__ b2,
                                                unsigned short* __restrict__ Cbf) {
    __shared__ float accs[2][64][36];          // 18 KB: kh=1 partials
    int tid = threadIdx.x;
    int w = tid >> 6, lane = tid & 63, col = lane & 15, g = lane >> 4;
    int ngw = w & 1, kh = w >> 1;
    int tb = blockIdx.x >> 2, nb = blockIdx.x & 3;
    int mw = tb * 32;                          // 32 tokens per wave
    int ntile0 = nb * 8 + ngw * 4;             // 4 n-tiles (64 n) per wave
    int kb32b = kh * 32;                       // this wave's k-half
    const short8 z8 = {0,0,0,0,0,0,0,0};
    const short8 one8 = {(short)0x3F80,0,0,0,0,0,0,0};
    const float4a zc = {0.f,0.f,0.f,0.f};

    short8 qf[2];                              // B[k=qslot][n=tok]; slot8 = 1.0
    #pragma unroll
    for (int t = 0; t < 2; t++)
        qf[t] = (g == 0) ? *(const short8*)&qbf[(size_t)(mw + t * 16 + col) * 8]
                         : (g == 1 ? one8 : z8);

    float4a acc[2][4];
    #pragma unroll
    for (int t = 0; t < 2; t++)
        #pragma unroll
        for (int nt = 0; nt < 4; nt++) acc[t][nt] = zc;

    const unsigned short* w2p = W2f + (size_t)ntile0 * 64 * 512 + lane * 8;
    // per-lane W1 base: g=0 -> W1 frag rows, g=1 -> b1 frag rows, g>=2 -> zeros
    const unsigned short* w1p =
        (g == 0) ? W1fg + (size_t)(kb32b * 32 + col) * 8 :
        (g == 1) ? W1fg + 16384 + (size_t)(kb32b * 32 + col) * 8 :
                   W1fg + 32768;
    int w1step = (g < 2) ? 256 : 0;            // u16 per kb32 iter

    short8 afA[4], afB[4], w1A0, w1A1, w1B0, w1B1;
    #pragma unroll
    for (int nt = 0; nt < 4; nt++)
        afA[nt] = *(const short8*)(w2p + nt * 32768 + (size_t)kb32b * 512);
    w1A0 = *(const short8*)w1p;
    w1A1 = *(const short8*)(w1p + 128);
    w1p += w1step;

#define FFN_BODY(AF, W10, W11)                                                    \
    {                                                                             \
        _Pragma("unroll")                                                         \
        for (int t = 0; t < 2; t++) {                                             \
            float4a h0 = __builtin_amdgcn_mfma_f32_16x16x32_bf16(W10, qf[t], zc, 0,0,0); \
            float4a h1 = __builtin_amdgcn_mfma_f32_16x16x32_bf16(W11, qf[t], zc, 0,0,0); \
            F4 H0, H1; H0.v = h0; H1.v = h1;                                      \
            float e00 = fmaxf(H0.f[0], 0.f);                                      \
            float e01 = fmaxf(H0.f[1], 0.f);                                      \
            float e02 = fmaxf(H0.f[2], 0.f);                                      \
            float e03 = fmaxf(H0.f[3], 0.f);                                      \
            float e10 = fmaxf(H1.f[0], 0.f);                                      \
            float e11 = fmaxf(H1.f[1], 0.f);                                      \
            float e12 = fmaxf(H1.f[2], 0.f);                                      \
            float e13 = fmaxf(H1.f[3], 0.f);                                      \
            U8 pf;                                                                \
            pf.u[0] = packbf(e01, e00);                                           \
            pf.u[1] = packbf(e03, e02);                                           \
            pf.u[2] = packbf(e11, e10);                                           \
            pf.u[3] = packbf(e13, e12);                                           \
            _Pragma("unroll")                                                     \
            for (int nt = 0; nt < 4; nt++)                                        \
                acc[t][nt] = __builtin_amdgcn_mfma_f32_16x16x32_bf16(AF[nt], pf.v, \
                                                                     acc[t][nt], 0,0,0); \
        }                                                                         \
    }

    for (int i = 0; i < 32; i += 2) {
        int kb32 = kb32b + i;
        // prefetch odd iter
        #pragma unroll
        for (int nt = 0; nt < 4; nt++)
            afB[nt] = *(const short8*)(w2p + nt * 32768 + (size_t)(kb32 + 1) * 512);
        w1B0 = *(const short8*)w1p;
        w1B1 = *(const short8*)(w1p + 128);
        w1p += w1step;
        FFN_BODY(afA, w1A0, w1A1)
        // prefetch next even iter (final round reads spill into adjacent
        // mapped workspace regions; values discarded)
        #pragma unroll
        for (int nt = 0; nt < 4; nt++)
            afA[nt] = *(const short8*)(w2p + nt * 32768 + (size_t)(kb32 + 2) * 512);
        w1A0 = *(const short8*)w1p;
        w1A1 = *(const short8*)(w1p + 128);
        w1p += w1step;
        FFN_BODY(afB, w1B0, w1B1)
    }
#undef FFN_BODY

    // combine k-halves: kh=1 waves publish, kh=0 waves reduce + store
    if (kh == 1) {
        #pragma unroll
        for (int t = 0; t < 2; t++)
            #pragma unroll
            for (int nt = 0; nt < 4; nt++)
                *(float4a*)&accs[ngw][lane][(t * 4 + nt) * 4] = acc[t][nt];
    }
    __syncthreads();
    if (kh == 0) {
        #pragma unroll
        for (int t = 0; t < 2; t++)
            #pragma unroll
            for (int nt = 0; nt < 4; nt++)
                acc[t][nt] = acc[t][nt] +
                    *(const float4a*)&accs[ngw][lane][(t * 4 + nt) * 4];
        int n0 = ntile0 * 16;
        #pragma unroll
        for (int nt = 0; nt < 4; nt++) {
            float4 bb = *(const float4*)&b2[n0 + nt * 16 + 4 * g];
            #pragma unroll
            for (int t = 0; t < 2; t++) {
                F4 a; a.v = acc[t][nt];
                uint2 o;
                o.x = packbf_rn(a.f[1] + bb.y, a.f[0] + bb.x);
                o.y = packbf_rn(a.f[3] + bb.w, a.f[2] + bb.z);
                *(uint2*)&Cbf[(size_t)(mw + t * 16 + col) * 512 + n0 + nt * 16 + 4 * g] = o;
            }
        }
    }
}

// ---------------------------------------------------------------------------
// K4: final LayerNorm — wave-per-token (no LDS, no syncthreads).
// grid 1024 x 256 thr; lane holds 8 elems; shfl_xor butterfly reduce.
// ---------------------------------------------------------------------------
__global__ __launch_bounds__(256) void ln_kernel(const float* __restrict__ a,
                                                 const unsigned short* __restrict__ r,
                                                 const float* __restrict__ g,
                                                 const float* __restrict__ be,
                                                 float* __restrict__ out) {
    int t = blockIdx.x * 4 + (threadIdx.x >> 6);
    int lane = threadIdx.x & 63;
    size_t base = (size_t)t * E;
    int e0 = lane * 8;
    float4 a0 = *(const float4*)&a[base + e0];
    float4 a1 = *(const float4*)&a[base + e0 + 4];
    uint4 rv = *(const uint4*)&r[base + e0];
    float v[8];
    v[0] = a0.x + bf2f((unsigned short)(rv.x & 0xffff));
    v[1] = a0.y + bf2f((unsigned short)(rv.x >> 16));
    v[2] = a0.z + bf2f((unsigned short)(rv.y & 0xffff));
    v[3] = a0.w + bf2f((unsigned short)(rv.y >> 16));
    v[4] = a1.x + bf2f((unsigned short)(rv.z & 0xffff));
    v[5] = a1.y + bf2f((unsigned short)(rv.z >> 16));
    v[6] = a1.z + bf2f((unsigned short)(rv.w & 0xffff));
    v[7] = a1.w + bf2f((unsigned short)(rv.w >> 16));
    float s = 0.f, sq = 0.f;
    #pragma unroll
    for (int i = 0; i < 8; i++) { s += v[i]; sq += v[i] * v[i]; }
    #pragma unroll
    for (int off = 1; off <= 32; off <<= 1) {
        s  += __shfl_xor(s, off);
        sq += __shfl_xor(sq, off);
    }
    float mu = s * (1.f / E);
    float var = sq * (1.f / E) - mu * mu;
    float rstd = rsqrtf(var + 1e-5f);
    float4 g0 = *(const float4*)&g[e0];
    float4 g1v = *(const float4*)&g[e0 + 4];
    float4 b0 = *(const float4*)&be[e0];
    float4 b1v = *(const float4*)&be[e0 + 4];
    float4 o0, o1;
    o0.x = (v[0] - mu) * rstd * g0.x + b0.x;
    o0.y = (v[1] - mu) * rstd * g0.y + b0.y;
    o0.z = (v[2] - mu) * rstd * g0.z + b0.z;
    o0.w = (v[3] - mu) * rstd * g0.w + b0.w;
    o1.x = (v[4] - mu) * rstd * g1v.x + b1v.x;
    o1.y = (v[5] - mu) * rstd * g1v.y + b1v.y;
    o1.z = (v[6] - mu) * rstd * g1v.z + b1v.z;
    o1.w = (v[7] - mu) * rstd * g1v.w + b1v.w;
    *(float4*)&out[base + e0] = o0;
    *(float4*)&out[base + e0 + 4] = o1;
}

// ---------------------------------------------------------------------------
// launch — 4 kernels. ws: Afrag/ffn_out 4MB | W2f 2MB | Wcf 0.5MB | W1f 128KB
// | qoutbf 64KB = 6.7 MB. d_out: x1 fp32, LN2 in-place.
// ---------------------------------------------------------------------------
extern "C" void kernel_launch(void* const* d_in, const int* in_sizes, int n_in,
                              void* d_out, int out_size, void* d_ws, size_t ws_size,
                              hipStream_t stream) {
    const float* x     = (const float*)d_in[0];
    const float* phi   = (const float*)d_in[1];
    const float* Wc    = (const float*)d_in[2];
    const float* bc    = (const float*)d_in[3];
    const float* theta = (const float*)d_in[4];
    const float* W1    = (const float*)d_in[5];
    const float* b1    = (const float*)d_in[6];
    const float* W2    = (const float*)d_in[7];
    const float* b2    = (const float*)d_in[8];
    const float* g1    = (const float*)d_in[9];
    const float* be1   = (const float*)d_in[10];
    const float* g2    = (const float*)d_in[11];
    const float* be2   = (const float*)d_in[12];
    float* out = (float*)d_out;

    float* ws = (float*)d_ws;
    unsigned short* Afrag  = (unsigned short*)ws;                       // 4 MB (also ffn_out)
    unsigned short* W2f    = (unsigned short*)(ws + 1048576);           // 2 MB
    unsigned short* Wcf    = (unsigned short*)(ws + 1572864);           // 512 KB
    unsigned short* W1f    = (unsigned short*)(ws + 1703936);           // 128 KB
    unsigned short* qoutbf = (unsigned short*)(ws + 1736704);           // 64 KB

    attn_conv_kernel<<<1360, 512, 0, stream>>>(x, phi, Wc, W2, W1, b1,
                                               Afrag, W2f, Wcf, W1f);
    combine_ln1<<<256, 512, 0, stream>>>(Afrag, Wcf, bc, x, g1, be1,
                                         out, qoutbf, theta);
    ffn_mfma<<<512, 256, 0, stream>>>(qoutbf, W1f, W2f, b2, Afrag);
    ln_kernel<<<1024, 256, 0, stream>>>(out, Afrag, g2, be2, out);
}